// Round 1
// baseline (50303.271 us; speedup 1.0000x reference)
//
#include <hip/hip_runtime.h>
#include <cstdint>
#include <cstddef>

#define Bz 64
#define Td 100
#define Sd 400
#define Ed 512
#define Hd 1024
#define Kd 512
#define Vd 34

__device__ __forceinline__ float sigmoidf_(float x) {
    return 1.0f / (1.0f + __expf(-x));
}
__device__ __forceinline__ float tanhf_(float x) {
    float e = __expf(-2.0f * fabsf(x));
    float r = (1.0f - e) / (1.0f + e);
    return copysignf(r, x);
}

// ---------------------------------------------------------------------------
// LSTM cell: gates[b][n] = sum_k in(b,k)*w_ih[n][k] + sum_k h_prev(b,k)*w_hh[n][k] + b_ih[n] + b_hh[n]
// Total reduce length 2048 (1024 input + 1024 recurrent) for every cell.
// mode 0: input = concat(emb[labels[b][t]], ctx[b])  (512 + 512)
// mode 1: input = h_in[b] (1024)
// Block: 256 threads = 4 cell-columns (jj) x 64 batches (b). Grid: 256 blocks.
// ---------------------------------------------------------------------------
__global__ __launch_bounds__(256) void cell_kernel(
    const float* __restrict__ xa,     // mode0: emb base; mode1: h_in
    const int* __restrict__ labels,   // mode0 only
    int t,
    const float* __restrict__ ctx,    // mode0 only
    const float* __restrict__ h_prev,
    float* c_state,                   // read+write, thread-local elements
    const float* __restrict__ w_ih, const float* __restrict__ w_hh,
    const float* __restrict__ b_ih, const float* __restrict__ b_hh,
    float* __restrict__ h_out,
    int mode)
{
    __shared__ float lds[64 * 129];   // 64 rows x 128 cols, stride 129 (2-way bank alias = free)
    const int tid = threadIdx.x;
    const int b   = tid & 63;
    const int jj  = tid >> 6;
    const int j   = (blockIdx.x << 2) + jj;

    float ai = 0.f, af = 0.f, ag = 0.f, ao = 0.f;

    for (int ch = 0; ch < 16; ++ch) {
        const int k0 = ch << 7;   // global k of chunk start, 0..1920
        __syncthreads();
        // cooperative load: 64 rows x 128 floats, float4-coalesced
        #pragma unroll
        for (int it = 0; it < 8; ++it) {
            int idx = (it << 8) + tid;       // 0..2047
            int row = idx >> 5;              // 0..63
            int c4  = (idx & 31) << 2;       // 0,4,...,124
            int kk  = k0 + c4;
            const float* src;
            if (mode == 0) {
                if (kk < Ed)        src = xa + (size_t)labels[row * Td + t] * Ed + kk;
                else if (kk < 1024) src = ctx + row * Kd + (kk - Ed);
                else                src = h_prev + row * Hd + (kk - 1024);
            } else {
                if (kk < 1024)      src = xa + row * Hd + kk;
                else                src = h_prev + row * Hd + (kk - 1024);
            }
            float4 v = *(const float4*)src;
            float* d = lds + row * 129 + c4;
            d[0] = v.x; d[1] = v.y; d[2] = v.z; d[3] = v.w;
        }
        __syncthreads();

        const float* wsrc = (k0 < 1024) ? w_ih : w_hh;
        const int kw = (k0 < 1024) ? k0 : (k0 - 1024);
        const float* w0 = wsrc + ((size_t)j)          * 1024 + kw;
        const float* w1 = wsrc + ((size_t)(1024 + j)) * 1024 + kw;
        const float* w2 = wsrc + ((size_t)(2048 + j)) * 1024 + kw;
        const float* w3 = wsrc + ((size_t)(3072 + j)) * 1024 + kw;
        const float* l  = lds + b * 129;
        #pragma unroll 4
        for (int k4 = 0; k4 < 32; ++k4) {
            float4 wi = *(const float4*)(w0 + (k4 << 2));
            float4 wf = *(const float4*)(w1 + (k4 << 2));
            float4 wg = *(const float4*)(w2 + (k4 << 2));
            float4 wo = *(const float4*)(w3 + (k4 << 2));
            float v0 = l[(k4 << 2) + 0];
            float v1 = l[(k4 << 2) + 1];
            float v2 = l[(k4 << 2) + 2];
            float v3 = l[(k4 << 2) + 3];
            ai += v0 * wi.x; ai += v1 * wi.y; ai += v2 * wi.z; ai += v3 * wi.w;
            af += v0 * wf.x; af += v1 * wf.y; af += v2 * wf.z; af += v3 * wf.w;
            ag += v0 * wg.x; ag += v1 * wg.y; ag += v2 * wg.z; ag += v3 * wg.w;
            ao += v0 * wo.x; ao += v1 * wo.y; ao += v2 * wo.z; ao += v3 * wo.w;
        }
    }

    ai += b_ih[j]        + b_hh[j];
    af += b_ih[1024 + j] + b_hh[1024 + j];
    ag += b_ih[2048 + j] + b_hh[2048 + j];
    ao += b_ih[3072 + j] + b_hh[3072 + j];

    float ig = sigmoidf_(ai);
    float fg = sigmoidf_(af);
    float og = sigmoidf_(ao);
    float gg = tanhf_(ag);
    int off = b * Hd + j;
    float cn = fg * c_state[off] + ig * gg;
    c_state[off] = cn;
    h_out[off] = og * tanhf_(cn);
}

// ---------------------------------------------------------------------------
// q[b][j] = b_proj[j] + sum_k h3[b][k] * w_proj[j][k]   (j < 512, k < 1024)
// Grid 128 blocks x 256 threads; same layout as cell_kernel with 1 accumulator.
// ---------------------------------------------------------------------------
__global__ __launch_bounds__(256) void q_kernel(
    const float* __restrict__ h3, const float* __restrict__ w_proj,
    const float* __restrict__ b_proj, float* __restrict__ q)
{
    __shared__ float lds[64 * 129];
    const int tid = threadIdx.x;
    const int b   = tid & 63;
    const int jj  = tid >> 6;
    const int j   = (blockIdx.x << 2) + jj;

    float acc = 0.f;
    for (int ch = 0; ch < 8; ++ch) {
        const int k0 = ch << 7;
        __syncthreads();
        #pragma unroll
        for (int it = 0; it < 8; ++it) {
            int idx = (it << 8) + tid;
            int row = idx >> 5;
            int c4  = (idx & 31) << 2;
            float4 v = *(const float4*)(h3 + row * Hd + k0 + c4);
            float* d = lds + row * 129 + c4;
            d[0] = v.x; d[1] = v.y; d[2] = v.z; d[3] = v.w;
        }
        __syncthreads();
        const float* w0 = w_proj + (size_t)j * 1024 + k0;
        const float* l  = lds + b * 129;
        #pragma unroll 4
        for (int k4 = 0; k4 < 32; ++k4) {
            float4 wv = *(const float4*)(w0 + (k4 << 2));
            acc += l[(k4 << 2) + 0] * wv.x;
            acc += l[(k4 << 2) + 1] * wv.y;
            acc += l[(k4 << 2) + 2] * wv.z;
            acc += l[(k4 << 2) + 3] * wv.w;
        }
    }
    q[b * Kd + j] = acc + b_proj[j];
}

// ---------------------------------------------------------------------------
// Energy + online-softmax partials + weighted value partial sums.
// Grid 512 = 64 b x 8 s-chunks (50 s each). Writes unnormalized exp() to the
// attention output slot; finalize_kernel rescales in place.
// ---------------------------------------------------------------------------
__global__ __launch_bounds__(256) void energy_kernel(
    const float* __restrict__ q, const float* __restrict__ keys,
    const float* __restrict__ values,
    float* __restrict__ attn, int t,
    float* __restrict__ u_part, float* __restrict__ m_part, float* __restrict__ z_part)
{
    __shared__ float qs[4 * 132];   // q skewed by 128-chunk to avoid 4-way same-bank
    __shared__ float es[64];
    __shared__ float ps[64];
    __shared__ float mz[1];
    const int tid = threadIdx.x;
    const int b   = blockIdx.x >> 3;
    const int ch  = blockIdx.x & 7;

    for (int k = tid; k < 512; k += 256)
        qs[(k >> 7) * 132 + (k & 127)] = q[b * Kd + k];
    __syncthreads();

    if (tid < 200) {
        int sl = tid >> 2, part = tid & 3;
        int s = ch * 50 + sl;
        const float* kr = keys + ((size_t)s * Bz + b) * Kd + part * 128;
        const float* qp = qs + part * 132;
        float e = 0.f;
        #pragma unroll 8
        for (int i4 = 0; i4 < 32; ++i4) {
            float4 kv = *(const float4*)(kr + (i4 << 2));
            e += qp[(i4 << 2) + 0] * kv.x;
            e += qp[(i4 << 2) + 1] * kv.y;
            e += qp[(i4 << 2) + 2] * kv.z;
            e += qp[(i4 << 2) + 3] * kv.w;
        }
        e += __shfl_down(e, 1);
        e += __shfl_down(e, 2);
        if (part == 0) es[sl] = e;
    }
    __syncthreads();
    if (tid == 0) {
        float m = -1e30f;
        for (int i = 0; i < 50; ++i) m = fmaxf(m, es[i]);
        mz[0] = m;
    }
    __syncthreads();
    float m = mz[0];
    if (tid < 50) {
        float p = __expf(es[tid] - m);
        ps[tid] = p;
        attn[(size_t)b * (Td * Sd) + t * Sd + ch * 50 + tid] = p;  // unnormalized
    }
    __syncthreads();
    if (tid == 0) {
        float z = 0.f;
        for (int i = 0; i < 50; ++i) z += ps[i];
        m_part[b * 8 + ch] = m;
        z_part[b * 8 + ch] = z;
    }
    // u_c[k] = sum_s p_s * values[s][b][k]
    float u0 = 0.f, u1 = 0.f;
    const float* vbase = values + ((size_t)(ch * 50) * Bz + b) * Kd;
    for (int s = 0; s < 50; ++s) {
        const float* vr = vbase + (size_t)s * Bz * Kd;
        float p = ps[s];
        u0 += p * vr[tid];
        u1 += p * vr[tid + 256];
    }
    u_part[((b << 3) + ch) * 512 + tid]       = u0;
    u_part[((b << 3) + ch) * 512 + tid + 256] = u1;
}

// ---------------------------------------------------------------------------
// Combine softmax partials -> ctx; normalize attention row in place; score.
// Grid 64 blocks (one per batch) x 256 threads.
// ---------------------------------------------------------------------------
__global__ __launch_bounds__(256) void finalize_kernel(
    const float* __restrict__ q, const float* __restrict__ u_part,
    const float* __restrict__ m_part, const float* __restrict__ z_part,
    float* __restrict__ ctx, float* __restrict__ attn, float* __restrict__ pred,
    const float* __restrict__ w_score, const float* __restrict__ b_score, int t)
{
    __shared__ float fc[8];
    __shared__ float qs[512];
    __shared__ float cs[512];
    const int tid = threadIdx.x;
    const int b = blockIdx.x;

    if (tid == 0) {
        float M = -1e30f;
        for (int c = 0; c < 8; ++c) M = fmaxf(M, m_part[b * 8 + c]);
        float f[8];
        float Z = 0.f;
        for (int c = 0; c < 8; ++c) {
            f[c] = __expf(m_part[b * 8 + c] - M);
            Z += z_part[b * 8 + c] * f[c];
        }
        float inv = 1.0f / Z;
        for (int c = 0; c < 8; ++c) fc[c] = f[c] * inv;
    }
    __syncthreads();

    for (int k = tid; k < 512; k += 256) {
        float acc = 0.f;
        #pragma unroll
        for (int c = 0; c < 8; ++c)
            acc += u_part[((b << 3) + c) * 512 + k] * fc[c];
        ctx[b * Kd + k] = acc;
        cs[k] = acc;
        qs[k] = q[b * Kd + k];
    }
    for (int s = tid; s < Sd; s += 256) {
        attn[(size_t)b * (Td * Sd) + t * Sd + s] *= fc[s / 50];
    }
    __syncthreads();

    if (tid < 136) {
        int v = tid >> 2, part = tid & 3;
        const float* wr = w_score + (size_t)v * 1024 + part * 256;
        const float* src = (part < 2) ? (qs + part * 256) : (cs + (part - 2) * 256);
        float acc = 0.f;
        #pragma unroll 8
        for (int i = 0; i < 256; ++i) acc += src[i] * wr[i];
        acc += __shfl_down(acc, 1);
        acc += __shfl_down(acc, 2);
        if (part == 0) pred[(size_t)b * (Td * Vd) + t * Vd + v] = acc + b_score[v];
    }
}

// ---------------------------------------------------------------------------
__global__ void init_states(const float* __restrict__ h0,
    float* h1, float* h2, float* h3, float* c1, float* c2, float* c3)
{
    int idx = blockIdx.x * 256 + threadIdx.x;   // < 6*65536
    int arr = idx >> 16;
    int off = idx & 65535;
    float v = h0[off & 1023];
    float* p;
    switch (arr) {
        case 0: p = h1; break;
        case 1: p = h2; break;
        case 2: p = h3; break;
        case 3: p = c1; break;
        case 4: p = c2; break;
        default: p = c3; break;
    }
    p[off] = v;
}

__global__ void init_ctx(const float* __restrict__ h0, const float* __restrict__ w_proj,
                         const float* __restrict__ b_proj, float* __restrict__ ctx)
{
    int k = blockIdx.x * 256 + threadIdx.x;   // < 512
    float acc = b_proj[k];
    const float* wr = w_proj + (size_t)k * 1024;
    for (int j = 0; j < 1024; ++j) acc += h0[j] * wr[j];
    for (int b = 0; b < Bz; ++b) ctx[b * Kd + k] = acc;
}

// ---------------------------------------------------------------------------
extern "C" void kernel_launch(void* const* d_in, const int* in_sizes, int n_in,
                              void* d_out, int out_size, void* d_ws, size_t ws_size,
                              hipStream_t stream)
{
    (void)in_sizes; (void)n_in; (void)out_size; (void)ws_size;
    const int*   labels = (const int*)d_in[0];
    const float* keys   = (const float*)d_in[1];
    const float* values = (const float*)d_in[2];
    const float* emb    = (const float*)d_in[3];
    const float* w_ih0  = (const float*)d_in[4];
    const float* w_hh0  = (const float*)d_in[5];
    const float* b_ih0  = (const float*)d_in[6];
    const float* b_hh0  = (const float*)d_in[7];
    const float* w_ih1  = (const float*)d_in[8];
    const float* w_hh1  = (const float*)d_in[9];
    const float* b_ih1  = (const float*)d_in[10];
    const float* b_hh1  = (const float*)d_in[11];
    const float* w_ih2  = (const float*)d_in[12];
    const float* w_hh2  = (const float*)d_in[13];
    const float* b_ih2  = (const float*)d_in[14];
    const float* b_hh2  = (const float*)d_in[15];
    const float* w_proj = (const float*)d_in[16];
    const float* b_proj = (const float*)d_in[17];
    const float* w_score= (const float*)d_in[18];
    const float* b_score= (const float*)d_in[19];
    const float* h0     = (const float*)d_in[20];

    float* ws = (float*)d_ws;
    float* h1[2] = { ws + 0,      ws + 65536 };
    float* h2[2] = { ws + 131072, ws + 196608 };
    float* h3[2] = { ws + 262144, ws + 327680 };
    float* c1 = ws + 393216;
    float* c2 = ws + 458752;
    float* c3 = ws + 524288;
    float* ctx = ws + 589824;   // 64x512
    float* q   = ws + 622592;   // 64x512
    float* u_part = ws + 655360; // 64x8x512
    float* m_part = ws + 917504; // 512
    float* z_part = ws + 918016; // 512

    float* pred = (float*)d_out;                       // [B,T,V]
    float* attn = (float*)d_out + (size_t)Bz * Td * Vd; // [B,T,S]

    init_states<<<1536, 256, 0, stream>>>(h0, h1[0], h2[0], h3[0], c1, c2, c3);
    init_ctx<<<2, 256, 0, stream>>>(h0, w_proj, b_proj, ctx);

    for (int t = 0; t < Td; ++t) {
        const int rb = t & 1, wb = 1 - rb;
        cell_kernel<<<256, 256, 0, stream>>>(emb, labels, t, ctx,
                                             h1[rb], c1, w_ih0, w_hh0, b_ih0, b_hh0,
                                             h1[wb], 0);
        cell_kernel<<<256, 256, 0, stream>>>(h1[wb], nullptr, t, nullptr,
                                             h2[rb], c2, w_ih1, w_hh1, b_ih1, b_hh1,
                                             h2[wb], 1);
        cell_kernel<<<256, 256, 0, stream>>>(h2[wb], nullptr, t, nullptr,
                                             h3[rb], c3, w_ih2, w_hh2, b_ih2, b_hh2,
                                             h3[wb], 1);
        q_kernel<<<128, 256, 0, stream>>>(h3[wb], w_proj, b_proj, q);
        energy_kernel<<<512, 256, 0, stream>>>(q, keys, values, attn, t,
                                               u_part, m_part, z_part);
        finalize_kernel<<<64, 256, 0, stream>>>(q, u_part, m_part, z_part,
                                                ctx, attn, pred, w_score, b_score, t);
    }
}

// Round 2
// 16517.136 us; speedup vs baseline: 3.0455x; 3.0455x over previous
//
#include <hip/hip_runtime.h>
#include <cstdint>
#include <cstddef>

#define Bz 64
#define Td 100
#define Sd 400
#define Ed 512
#define Hd 1024
#define Kd 512
#define Vd 34

__device__ __forceinline__ float sigmoidf_(float x) {
    return 1.0f / (1.0f + __expf(-x));
}
__device__ __forceinline__ float tanhf_(float x) {
    float e = __expf(-2.0f * fabsf(x));
    float r = (1.0f - e) / (1.0f + e);
    return copysignf(r, x);
}

// ---------------------------------------------------------------------------
// Split-K LSTM-cell GEMM. gates[b][g*1024+j] partial over one 512-wide k-slice.
// Grid 512 = jg(64) x ks(4) x bh(2). Block 256 thr = bq(16) x jl(16).
// Thread tile: 4 gates x 2 batches (b = bh*32 + bq, +16). k-slice: 512 as
// 4 LDS-staged sub-chunks of 128.
// k layout (2048): mode0: [emb(512) | ctx(512) | h_prev(1024)]
//                  mode1: [h_in(1024) | h_prev(1024)]
// ks 0,1 -> w_ih cols 0:512 / 512:1024 ; ks 2,3 -> w_hh cols 0:512 / 512:1024
// ---------------------------------------------------------------------------
__global__ __launch_bounds__(256) void gemm_cell(
    const float* __restrict__ src0,   // mode0: emb base ; mode1: h_in
    const int* __restrict__ labels, int t,
    const float* __restrict__ ctx,    // mode0 only
    const float* __restrict__ h_prev,
    const float* __restrict__ w_ih, const float* __restrict__ w_hh,
    float* __restrict__ gpart, int mode)
{
    __shared__ float lds[32 * 132];   // 32 b-rows x 128 k, stride 132 (16B-aligned, 2-way bank alias)
    const int tid = threadIdx.x;
    const int bq  = tid & 15;
    const int jl  = tid >> 4;
    const int bid = blockIdx.x;
    const int jg  = bid & 63;
    const int ks  = (bid >> 6) & 3;
    const int bh  = bid >> 8;
    const int j   = jg * 16 + jl;
    const int b0  = bh * 32;

    const float* wsrc = (ks < 2) ? w_ih : w_hh;
    const int koff = (ks & 1) * 512;
    const float* w0 = wsrc + ((size_t)j)          * 1024 + koff;
    const float* w1 = wsrc + ((size_t)(1024 + j)) * 1024 + koff;
    const float* w2 = wsrc + ((size_t)(2048 + j)) * 1024 + koff;
    const float* w3 = wsrc + ((size_t)(3072 + j)) * 1024 + koff;

    float acc00 = 0.f, acc01 = 0.f, acc02 = 0.f, acc03 = 0.f;   // b = b0+bq
    float acc10 = 0.f, acc11 = 0.f, acc12 = 0.f, acc13 = 0.f;   // b = b0+bq+16

    for (int sub = 0; sub < 4; ++sub) {
        __syncthreads();
        // stage 32 rows x 128 k: 1024 float4 / 256 thr = 4 each
        #pragma unroll
        for (int it = 0; it < 4; ++it) {
            int idx = (it << 8) + tid;
            int r   = idx >> 5;
            int c4  = (idx & 31) << 2;
            int b   = b0 + r;
            const float* src;
            if (mode == 0) {
                if (ks == 0)      src = src0 + (size_t)labels[b * Td + t] * Ed + (sub << 7) + c4;
                else if (ks == 1) src = ctx + b * Kd + (sub << 7) + c4;
                else              src = h_prev + b * Hd + ((ks - 2) << 9) + (sub << 7) + c4;
            } else {
                if (ks < 2)       src = src0 + b * Hd + (ks << 9) + (sub << 7) + c4;
                else              src = h_prev + b * Hd + ((ks - 2) << 9) + (sub << 7) + c4;
            }
            float4 v = *(const float4*)src;
            float* d = lds + r * 132 + c4;
            d[0] = v.x; d[1] = v.y; d[2] = v.z; d[3] = v.w;
        }
        __syncthreads();

        const float* wp0 = w0 + (sub << 7);
        const float* wp1 = w1 + (sub << 7);
        const float* wp2 = w2 + (sub << 7);
        const float* wp3 = w3 + (sub << 7);
        const float* l0  = lds + bq * 132;
        const float* l1  = lds + (bq + 16) * 132;
        #pragma unroll 4
        for (int k4 = 0; k4 < 32; ++k4) {
            float4 wv0 = *(const float4*)(wp0 + (k4 << 2));
            float4 wv1 = *(const float4*)(wp1 + (k4 << 2));
            float4 wv2 = *(const float4*)(wp2 + (k4 << 2));
            float4 wv3 = *(const float4*)(wp3 + (k4 << 2));
            float4 a0  = *(const float4*)(l0 + (k4 << 2));
            float4 a1  = *(const float4*)(l1 + (k4 << 2));
            acc00 += a0.x*wv0.x; acc00 += a0.y*wv0.y; acc00 += a0.z*wv0.z; acc00 += a0.w*wv0.w;
            acc01 += a0.x*wv1.x; acc01 += a0.y*wv1.y; acc01 += a0.z*wv1.z; acc01 += a0.w*wv1.w;
            acc02 += a0.x*wv2.x; acc02 += a0.y*wv2.y; acc02 += a0.z*wv2.z; acc02 += a0.w*wv2.w;
            acc03 += a0.x*wv3.x; acc03 += a0.y*wv3.y; acc03 += a0.z*wv3.z; acc03 += a0.w*wv3.w;
            acc10 += a1.x*wv0.x; acc10 += a1.y*wv0.y; acc10 += a1.z*wv0.z; acc10 += a1.w*wv0.w;
            acc11 += a1.x*wv1.x; acc11 += a1.y*wv1.y; acc11 += a1.z*wv1.z; acc11 += a1.w*wv1.w;
            acc12 += a1.x*wv2.x; acc12 += a1.y*wv2.y; acc12 += a1.z*wv2.z; acc12 += a1.w*wv2.w;
            acc13 += a1.x*wv3.x; acc13 += a1.y*wv3.y; acc13 += a1.z*wv3.z; acc13 += a1.w*wv3.w;
        }
    }

    const size_t rowA = ((size_t)ks * 64 + b0 + bq) * 4096;
    const size_t rowB = ((size_t)ks * 64 + b0 + bq + 16) * 4096;
    gpart[rowA + 0 * 1024 + j] = acc00;
    gpart[rowA + 1 * 1024 + j] = acc01;
    gpart[rowA + 2 * 1024 + j] = acc02;
    gpart[rowA + 3 * 1024 + j] = acc03;
    gpart[rowB + 0 * 1024 + j] = acc10;
    gpart[rowB + 1 * 1024 + j] = acc11;
    gpart[rowB + 2 * 1024 + j] = acc12;
    gpart[rowB + 3 * 1024 + j] = acc13;
}

// ---------------------------------------------------------------------------
// Sum 4 k-slice partials + biases, LSTM pointwise, write h and c.
// Grid 256 x 256 thr, 1 element each (65536 = 64b x 1024j).
// ---------------------------------------------------------------------------
__global__ __launch_bounds__(256) void combine_cell(
    const float* __restrict__ gpart,
    const float* __restrict__ b_ih, const float* __restrict__ b_hh,
    float* c, float* __restrict__ h)
{
    int el = blockIdx.x * 256 + threadIdx.x;
    int b = el >> 10, j = el & 1023;
    float g[4];
    #pragma unroll
    for (int gi = 0; gi < 4; ++gi) {
        float s = b_ih[gi * 1024 + j] + b_hh[gi * 1024 + j];
        #pragma unroll
        for (int ksi = 0; ksi < 4; ++ksi)
            s += gpart[((size_t)ksi * 64 + b) * 4096 + gi * 1024 + j];
        g[gi] = s;
    }
    float ig = sigmoidf_(g[0]);
    float fg = sigmoidf_(g[1]);
    float gg = tanhf_(g[2]);
    float og = sigmoidf_(g[3]);
    float cn = fg * c[el] + ig * gg;
    c[el] = cn;
    h[el] = og * tanhf_(cn);
}

// ---------------------------------------------------------------------------
// q partial GEMM: qpart[ks][b][n] over k-slice of 256.
// Grid 256 = ng(32) x ks(4) x bh(2). Block 256 = bq(16) x nl(16).
// Thread tile 1 n x 2 b.
// ---------------------------------------------------------------------------
__global__ __launch_bounds__(256) void gemm_q(
    const float* __restrict__ h3, const float* __restrict__ w_proj,
    float* __restrict__ qpart)
{
    __shared__ float lds[32 * 132];
    const int tid = threadIdx.x;
    const int bq = tid & 15, nl = tid >> 4;
    const int bid = blockIdx.x;
    const int ng = bid & 31, ks = (bid >> 5) & 3, bh = bid >> 7;
    const int n = ng * 16 + nl;
    const int b0 = bh * 32;
    const float* wp = w_proj + (size_t)n * 1024 + (ks << 8);

    float acc0 = 0.f, acc1 = 0.f;
    for (int sub = 0; sub < 2; ++sub) {
        __syncthreads();
        #pragma unroll
        for (int it = 0; it < 4; ++it) {
            int idx = (it << 8) + tid;
            int r = idx >> 5, c4 = (idx & 31) << 2;
            float4 v = *(const float4*)(h3 + (size_t)(b0 + r) * 1024 + (ks << 8) + (sub << 7) + c4);
            float* d = lds + r * 132 + c4;
            d[0] = v.x; d[1] = v.y; d[2] = v.z; d[3] = v.w;
        }
        __syncthreads();
        const float* l0 = lds + bq * 132;
        const float* l1 = lds + (bq + 16) * 132;
        const float* wq = wp + (sub << 7);
        #pragma unroll 4
        for (int k4 = 0; k4 < 32; ++k4) {
            float4 wv = *(const float4*)(wq + (k4 << 2));
            float4 a0 = *(const float4*)(l0 + (k4 << 2));
            float4 a1 = *(const float4*)(l1 + (k4 << 2));
            acc0 += a0.x*wv.x; acc0 += a0.y*wv.y; acc0 += a0.z*wv.z; acc0 += a0.w*wv.w;
            acc1 += a1.x*wv.x; acc1 += a1.y*wv.y; acc1 += a1.z*wv.z; acc1 += a1.w*wv.w;
        }
    }
    qpart[((size_t)ks * 64 + b0 + bq) * 512 + n]      = acc0;
    qpart[((size_t)ks * 64 + b0 + bq + 16) * 512 + n] = acc1;
}

// ---------------------------------------------------------------------------
// Energy + online-softmax partials + weighted value partial sums.
// Grid 512 = 64 b x 8 s-chunks (50 s each). q re-summed from qpart in prologue.
// ---------------------------------------------------------------------------
__global__ __launch_bounds__(256) void energy_kernel(
    const float* __restrict__ qpart, const float* __restrict__ b_proj,
    const float* __restrict__ keys, const float* __restrict__ values,
    float* __restrict__ attn, int t,
    float* __restrict__ u_part, float* __restrict__ m_part, float* __restrict__ z_part)
{
    __shared__ float qs[4 * 132];
    __shared__ float es[64];
    __shared__ float ps[64];
    __shared__ float mz[1];
    const int tid = threadIdx.x;
    const int b   = blockIdx.x >> 3;
    const int ch  = blockIdx.x & 7;

    for (int k = tid; k < 512; k += 256) {
        float s = b_proj[k];
        #pragma unroll
        for (int ksi = 0; ksi < 4; ++ksi)
            s += qpart[((size_t)ksi * 64 + b) * 512 + k];
        qs[(k >> 7) * 132 + (k & 127)] = s;
    }
    __syncthreads();

    if (tid < 200) {
        int sl = tid >> 2, part = tid & 3;
        int s = ch * 50 + sl;
        const float* kr = keys + ((size_t)s * Bz + b) * Kd + part * 128;
        const float* qp = qs + part * 132;
        float e = 0.f;
        #pragma unroll 8
        for (int i4 = 0; i4 < 32; ++i4) {
            float4 kv = *(const float4*)(kr + (i4 << 2));
            e += qp[(i4 << 2) + 0] * kv.x;
            e += qp[(i4 << 2) + 1] * kv.y;
            e += qp[(i4 << 2) + 2] * kv.z;
            e += qp[(i4 << 2) + 3] * kv.w;
        }
        e += __shfl_down(e, 1);
        e += __shfl_down(e, 2);
        if (part == 0) es[sl] = e;
    }
    __syncthreads();
    if (tid == 0) {
        float m = -1e30f;
        for (int i = 0; i < 50; ++i) m = fmaxf(m, es[i]);
        mz[0] = m;
    }
    __syncthreads();
    float m = mz[0];
    if (tid < 50) {
        float p = __expf(es[tid] - m);
        ps[tid] = p;
        attn[(size_t)b * (Td * Sd) + t * Sd + ch * 50 + tid] = p;  // unnormalized
    }
    __syncthreads();
    if (tid == 0) {
        float z = 0.f;
        for (int i = 0; i < 50; ++i) z += ps[i];
        m_part[b * 8 + ch] = m;
        z_part[b * 8 + ch] = z;
    }
    float u0 = 0.f, u1 = 0.f;
    const float* vbase = values + ((size_t)(ch * 50) * Bz + b) * Kd;
    for (int s = 0; s < 50; ++s) {
        const float* vr = vbase + (size_t)s * Bz * Kd;
        float p = ps[s];
        u0 += p * vr[tid];
        u1 += p * vr[tid + 256];
    }
    u_part[((b << 3) + ch) * 512 + tid]       = u0;
    u_part[((b << 3) + ch) * 512 + tid + 256] = u1;
}

// ---------------------------------------------------------------------------
// Combine softmax partials -> ctx; normalize attention row; score.
// Grid 64 blocks (one per batch) x 256 threads.
// ---------------------------------------------------------------------------
__global__ __launch_bounds__(256) void finalize_kernel(
    const float* __restrict__ qpart, const float* __restrict__ b_proj,
    const float* __restrict__ u_part,
    const float* __restrict__ m_part, const float* __restrict__ z_part,
    float* __restrict__ ctx, float* __restrict__ attn, float* __restrict__ pred,
    const float* __restrict__ w_score, const float* __restrict__ b_score, int t)
{
    __shared__ float fc[8];
    __shared__ float qs[512];
    __shared__ float cs[512];
    const int tid = threadIdx.x;
    const int b = blockIdx.x;

    if (tid == 0) {
        float M = -1e30f;
        for (int c = 0; c < 8; ++c) M = fmaxf(M, m_part[b * 8 + c]);
        float f[8];
        float Z = 0.f;
        for (int c = 0; c < 8; ++c) {
            f[c] = __expf(m_part[b * 8 + c] - M);
            Z += z_part[b * 8 + c] * f[c];
        }
        float inv = 1.0f / Z;
        for (int c = 0; c < 8; ++c) fc[c] = f[c] * inv;
    }
    __syncthreads();

    for (int k = tid; k < 512; k += 256) {
        float s = b_proj[k];
        #pragma unroll
        for (int ksi = 0; ksi < 4; ++ksi)
            s += qpart[((size_t)ksi * 64 + b) * 512 + k];
        qs[k] = s;
        float acc = 0.f;
        #pragma unroll
        for (int c = 0; c < 8; ++c)
            acc += u_part[((b << 3) + c) * 512 + k] * fc[c];
        ctx[b * Kd + k] = acc;
        cs[k] = acc;
    }
    for (int s = tid; s < Sd; s += 256) {
        attn[(size_t)b * (Td * Sd) + t * Sd + s] *= fc[s / 50];
    }
    __syncthreads();

    if (tid < 136) {
        int v = tid >> 2, part = tid & 3;
        const float* wr = w_score + (size_t)v * 1024 + part * 256;
        const float* src = (part < 2) ? (qs + part * 256) : (cs + (part - 2) * 256);
        float acc = 0.f;
        #pragma unroll 8
        for (int i = 0; i < 256; ++i) acc += src[i] * wr[i];
        acc += __shfl_down(acc, 1);
        acc += __shfl_down(acc, 2);
        if (part == 0) pred[(size_t)b * (Td * Vd) + t * Vd + v] = acc + b_score[v];
    }
}

// ---------------------------------------------------------------------------
__global__ void init_states(const float* __restrict__ h0,
    float* h1, float* h2, float* h3, float* c1, float* c2, float* c3)
{
    int idx = blockIdx.x * 256 + threadIdx.x;   // < 6*65536
    int arr = idx >> 16;
    int off = idx & 65535;
    float v = h0[off & 1023];
    float* p;
    switch (arr) {
        case 0: p = h1; break;
        case 1: p = h2; break;
        case 2: p = h3; break;
        case 3: p = c1; break;
        case 4: p = c2; break;
        default: p = c3; break;
    }
    p[off] = v;
}

__global__ void init_ctx(const float* __restrict__ h0, const float* __restrict__ w_proj,
                         const float* __restrict__ b_proj, float* __restrict__ ctx)
{
    int k = blockIdx.x * 256 + threadIdx.x;   // < 512
    float acc = b_proj[k];
    const float* wr = w_proj + (size_t)k * 1024;
    for (int j = 0; j < 1024; ++j) acc += h0[j] * wr[j];
    for (int b = 0; b < Bz; ++b) ctx[b * Kd + k] = acc;
}

// ---------------------------------------------------------------------------
extern "C" void kernel_launch(void* const* d_in, const int* in_sizes, int n_in,
                              void* d_out, int out_size, void* d_ws, size_t ws_size,
                              hipStream_t stream)
{
    (void)in_sizes; (void)n_in; (void)out_size; (void)ws_size;
    const int*   labels = (const int*)d_in[0];
    const float* keys   = (const float*)d_in[1];
    const float* values = (const float*)d_in[2];
    const float* emb    = (const float*)d_in[3];
    const float* w_ih0  = (const float*)d_in[4];
    const float* w_hh0  = (const float*)d_in[5];
    const float* b_ih0  = (const float*)d_in[6];
    const float* b_hh0  = (const float*)d_in[7];
    const float* w_ih1  = (const float*)d_in[8];
    const float* w_hh1  = (const float*)d_in[9];
    const float* b_ih1  = (const float*)d_in[10];
    const float* b_hh1  = (const float*)d_in[11];
    const float* w_ih2  = (const float*)d_in[12];
    const float* w_hh2  = (const float*)d_in[13];
    const float* b_ih2  = (const float*)d_in[14];
    const float* b_hh2  = (const float*)d_in[15];
    const float* w_proj = (const float*)d_in[16];
    const float* b_proj = (const float*)d_in[17];
    const float* w_score= (const float*)d_in[18];
    const float* b_score= (const float*)d_in[19];
    const float* h0     = (const float*)d_in[20];

    float* ws = (float*)d_ws;
    float* h1 = ws + 0;
    float* h2 = ws + 65536;
    float* h3 = ws + 131072;
    float* c1 = ws + 196608;
    float* c2 = ws + 262144;
    float* c3 = ws + 327680;
    float* ctx = ws + 393216;     // 64x512
    float* gpart = ws + 425984;   // 4 x 64 x 4096
    float* qpart = ws + 1474560;  // 4 x 64 x 512
    float* u_part = ws + 1605632; // 64 x 8 x 512
    float* m_part = ws + 1867776; // 512
    float* z_part = ws + 1868288; // 512

    float* pred = (float*)d_out;                        // [B,T,V]
    float* attn = (float*)d_out + (size_t)Bz * Td * Vd; // [B,T,S]

    init_states<<<1536, 256, 0, stream>>>(h0, h1, h2, h3, c1, c2, c3);
    init_ctx<<<2, 256, 0, stream>>>(h0, w_proj, b_proj, ctx);

    for (int t = 0; t < Td; ++t) {
        gemm_cell<<<512, 256, 0, stream>>>(emb, labels, t, ctx, h1,
                                           w_ih0, w_hh0, gpart, 0);
        combine_cell<<<256, 256, 0, stream>>>(gpart, b_ih0, b_hh0, c1, h1);
        gemm_cell<<<512, 256, 0, stream>>>(h1, nullptr, 0, nullptr, h2,
                                           w_ih1, w_hh1, gpart, 1);
        combine_cell<<<256, 256, 0, stream>>>(gpart, b_ih1, b_hh1, c2, h2);
        gemm_cell<<<512, 256, 0, stream>>>(h2, nullptr, 0, nullptr, h3,
                                           w_ih2, w_hh2, gpart, 1);
        combine_cell<<<256, 256, 0, stream>>>(gpart, b_ih2, b_hh2, c3, h3);
        gemm_q<<<256, 256, 0, stream>>>(h3, w_proj, qpart);
        energy_kernel<<<512, 256, 0, stream>>>(qpart, b_proj, keys, values, attn, t,
                                               u_part, m_part, z_part);
        finalize_kernel<<<64, 256, 0, stream>>>(qpart, b_proj, u_part, m_part, z_part,
                                                ctx, attn, pred, w_score, b_score, t);
    }
}

// Round 3
// 9498.109 us; speedup vs baseline: 5.2961x; 1.7390x over previous
//
#include <hip/hip_runtime.h>
#include <cstdint>
#include <cstddef>

#define Bz 64
#define Td 100
#define Sd 400
#define Ed 512
#define Hd 1024
#define Kd 512
#define Vd 34

typedef __attribute__((ext_vector_type(8))) short short8v;
typedef __attribute__((ext_vector_type(8))) unsigned short ushort8v;
typedef __attribute__((ext_vector_type(4))) float floatx4;

__device__ __forceinline__ float sigmoidf_(float x) {
    return 1.0f / (1.0f + __expf(-x));
}
__device__ __forceinline__ float tanhf_(float x) {
    float e = __expf(-2.0f * fabsf(x));
    float r = (1.0f - e) / (1.0f + e);
    return copysignf(r, x);
}
__device__ __forceinline__ unsigned short f2bf(float x) {
    unsigned int u = __float_as_uint(x);
    unsigned int r = (u + 0x7fffu + ((u >> 16) & 1u)) >> 16;
    return (unsigned short)r;
}
__device__ __forceinline__ float bf2f(unsigned short h) {
    return __uint_as_float(((unsigned int)h) << 16);
}

// ---------------------------------------------------------------------------
// Pack fp32 weight -> bf16 hi plane + bf16 lo plane (split-bf16).
// ---------------------------------------------------------------------------
__global__ __launch_bounds__(256) void pack_w_kernel(
    const float* __restrict__ w, unsigned short* __restrict__ hi,
    unsigned short* __restrict__ lo, int n4)
{
    int i = blockIdx.x * 256 + threadIdx.x;
    if (i >= n4) return;
    float4 v = ((const float4*)w)[i];
    float f[4] = {v.x, v.y, v.z, v.w};
    unsigned short h[4], l[4];
    #pragma unroll
    for (int e = 0; e < 4; ++e) {
        h[e] = f2bf(f[e]);
        l[e] = f2bf(f[e] - bf2f(h[e]));
    }
    ushort4 hv = {h[0], h[1], h[2], h[3]};
    ushort4 lv = {l[0], l[1], l[2], l[3]};
    ((ushort4*)hi)[i] = hv;
    ((ushort4*)lo)[i] = lv;
}

// ---------------------------------------------------------------------------
// Split-bf16 MFMA LSTM-cell GEMM (fast path).
// gates[b=64][n=4096] = X[64x2048] . W^T, K split in 8 slices of 256.
// Grid 256 = nt(32) x ks(8). Block 256 thr = 4 waves.
// Wave w: n-frags nA = nt*128 + w*16, nB = nA + 64; m-frags 0..3 (all 64 b).
// Per 32-k step: 3 MFMAs per (m,n) frag pair: xh*wh + xl*wh + xh*wl.
// X staged in LDS as bf16 hi/lo, row stride 264 ushorts (528B: 8-cy b128 floor).
// k layout (2048): mode0 [emb512|ctx512|h_prev1024], mode1 [h_in1024|h_prev1024]
// ks<4 -> w_ih col ks*256 ; ks>=4 -> w_hh col (ks-4)*256.
// ---------------------------------------------------------------------------
__global__ __launch_bounds__(256) void gemm_cell_mfma(
    const float* __restrict__ src0, const int* __restrict__ labels, int t,
    const float* __restrict__ ctx, const float* __restrict__ h_prev,
    const unsigned short* __restrict__ wih_hi, const unsigned short* __restrict__ wih_lo,
    const unsigned short* __restrict__ whh_hi, const unsigned short* __restrict__ whh_lo,
    float* __restrict__ gpart, int mode)
{
    __shared__ unsigned short xs[64 * 264];   // [row 0..63][16 groups x (8 hi | 8 lo)] + pad
    const int tid  = threadIdx.x;
    const int w    = tid >> 6;
    const int lane = tid & 63;
    const int quad = lane >> 4;
    const int l16  = lane & 15;
    const int nt   = blockIdx.x & 31;
    const int ks   = blockIdx.x >> 5;   // 0..7
    const int nA   = nt * 128 + w * 16;
    const int nB   = nA + 64;

    const unsigned short* whi = (ks < 4) ? wih_hi : whh_hi;
    const unsigned short* wlo = (ks < 4) ? wih_lo : whh_lo;
    const int kcol0 = (ks & 3) * 256;   // column base within the 1024-wide weight

    floatx4 zero = {0.f, 0.f, 0.f, 0.f};
    floatx4 accA[4] = {zero, zero, zero, zero};
    floatx4 accB[4] = {zero, zero, zero, zero};

    for (int kc = 0; kc < 2; ++kc) {
        __syncthreads();
        // ---- stage 64 rows x 128 k (fp32 -> bf16 hi/lo) ----
        #pragma unroll
        for (int it = 0; it < 4; ++it) {
            int p = it * 256 + tid;      // 0..1023 = row(64) x group(16)
            int r = p >> 4;
            int g = p & 15;
            int kg = kcol0 + kc * 128 + g * 8;   // col within weight k-range
            const float* srow;
            if (mode == 0) {
                if (ks < 2)      srow = src0 + (size_t)labels[r * Td + t] * Ed + kg;
                else if (ks < 4) srow = ctx + r * Kd + (kg - 512);
                else             srow = h_prev + r * Hd + kg;
            } else {
                if (ks < 4)      srow = src0 + r * Hd + kg;
                else             srow = h_prev + r * Hd + kg;
            }
            float4 v0 = *(const float4*)(srow);
            float4 v1 = *(const float4*)(srow + 4);
            float f[8] = {v0.x, v0.y, v0.z, v0.w, v1.x, v1.y, v1.z, v1.w};
            ushort8v H, L;
            #pragma unroll
            for (int e = 0; e < 8; ++e) {
                unsigned short h = f2bf(f[e]);
                H[e] = h;
                L[e] = f2bf(f[e] - bf2f(h));
            }
            unsigned short* dst = xs + r * 264 + g * 16;
            *(ushort8v*)dst       = H;
            *(ushort8v*)(dst + 8) = L;
        }
        __syncthreads();

        // ---- 4 k-steps of 32, with 1-step weight prefetch ----
        int kcol = kcol0 + kc * 128 + quad * 8;
        size_t rA = ((size_t)(nA + l16)) * 1024 + kcol;
        size_t rB = ((size_t)(nB + l16)) * 1024 + kcol;
        short8v bAh = *(const short8v*)(whi + rA);
        short8v bAl = *(const short8v*)(wlo + rA);
        short8v bBh = *(const short8v*)(whi + rB);
        short8v bBl = *(const short8v*)(wlo + rB);
        #pragma unroll
        for (int kk = 0; kk < 4; ++kk) {
            short8v cAh = bAh, cAl = bAl, cBh = bBh, cBl = bBl;
            if (kk < 3) {
                bAh = *(const short8v*)(whi + rA + 32 * (kk + 1));
                bAl = *(const short8v*)(wlo + rA + 32 * (kk + 1));
                bBh = *(const short8v*)(whi + rB + 32 * (kk + 1));
                bBl = *(const short8v*)(wlo + rB + 32 * (kk + 1));
            }
            #pragma unroll
            for (int mf = 0; mf < 4; ++mf) {
                const unsigned short* ar = xs + (mf * 16 + l16) * 264 + (kk * 4 + quad) * 16;
                short8v ah = *(const short8v*)ar;
                short8v al = *(const short8v*)(ar + 8);
                accA[mf] = __builtin_amdgcn_mfma_f32_16x16x32_bf16(ah, cAh, accA[mf], 0, 0, 0);
                accA[mf] = __builtin_amdgcn_mfma_f32_16x16x32_bf16(al, cAh, accA[mf], 0, 0, 0);
                accA[mf] = __builtin_amdgcn_mfma_f32_16x16x32_bf16(ah, cAl, accA[mf], 0, 0, 0);
                accB[mf] = __builtin_amdgcn_mfma_f32_16x16x32_bf16(ah, cBh, accB[mf], 0, 0, 0);
                accB[mf] = __builtin_amdgcn_mfma_f32_16x16x32_bf16(al, cBh, accB[mf], 0, 0, 0);
                accB[mf] = __builtin_amdgcn_mfma_f32_16x16x32_bf16(ah, cBl, accB[mf], 0, 0, 0);
            }
        }
    }

    // ---- epilogue: D row(m=batch) = quad*4+reg, col(n) = l16 ----
    #pragma unroll
    for (int mf = 0; mf < 4; ++mf) {
        int m = mf * 16 + quad * 4;
        float* gA = gpart + ((size_t)ks * 64 + m) * 4096 + nA + l16;
        float* gB = gpart + ((size_t)ks * 64 + m) * 4096 + nB + l16;
        #pragma unroll
        for (int reg = 0; reg < 4; ++reg) {
            gA[(size_t)reg * 4096] = accA[mf][reg];
            gB[(size_t)reg * 4096] = accB[mf][reg];
        }
    }
}

// ---------------------------------------------------------------------------
// Fallback split-K fp32 LSTM-cell GEMM (round-2 kernel, used if ws too small).
// ---------------------------------------------------------------------------
__global__ __launch_bounds__(256) void gemm_cell(
    const float* __restrict__ src0,
    const int* __restrict__ labels, int t,
    const float* __restrict__ ctx,
    const float* __restrict__ h_prev,
    const float* __restrict__ w_ih, const float* __restrict__ w_hh,
    float* __restrict__ gpart, int mode)
{
    __shared__ float lds[32 * 132];
    const int tid = threadIdx.x;
    const int bq  = tid & 15;
    const int jl  = tid >> 4;
    const int bid = blockIdx.x;
    const int jg  = bid & 63;
    const int ks  = (bid >> 6) & 3;
    const int bh  = bid >> 8;
    const int j   = jg * 16 + jl;
    const int b0  = bh * 32;

    const float* wsrc = (ks < 2) ? w_ih : w_hh;
    const int koff = (ks & 1) * 512;
    const float* w0 = wsrc + ((size_t)j)          * 1024 + koff;
    const float* w1 = wsrc + ((size_t)(1024 + j)) * 1024 + koff;
    const float* w2 = wsrc + ((size_t)(2048 + j)) * 1024 + koff;
    const float* w3 = wsrc + ((size_t)(3072 + j)) * 1024 + koff;

    float acc00 = 0.f, acc01 = 0.f, acc02 = 0.f, acc03 = 0.f;
    float acc10 = 0.f, acc11 = 0.f, acc12 = 0.f, acc13 = 0.f;

    for (int sub = 0; sub < 4; ++sub) {
        __syncthreads();
        #pragma unroll
        for (int it = 0; it < 4; ++it) {
            int idx = (it << 8) + tid;
            int r   = idx >> 5;
            int c4  = (idx & 31) << 2;
            int b   = b0 + r;
            const float* src;
            if (mode == 0) {
                if (ks == 0)      src = src0 + (size_t)labels[b * Td + t] * Ed + (sub << 7) + c4;
                else if (ks == 1) src = ctx + b * Kd + (sub << 7) + c4;
                else              src = h_prev + b * Hd + ((ks - 2) << 9) + (sub << 7) + c4;
            } else {
                if (ks < 2)       src = src0 + b * Hd + (ks << 9) + (sub << 7) + c4;
                else              src = h_prev + b * Hd + ((ks - 2) << 9) + (sub << 7) + c4;
            }
            float4 v = *(const float4*)src;
            float* d = lds + r * 132 + c4;
            d[0] = v.x; d[1] = v.y; d[2] = v.z; d[3] = v.w;
        }
        __syncthreads();

        const float* wp0 = w0 + (sub << 7);
        const float* wp1 = w1 + (sub << 7);
        const float* wp2 = w2 + (sub << 7);
        const float* wp3 = w3 + (sub << 7);
        const float* l0  = lds + bq * 132;
        const float* l1  = lds + (bq + 16) * 132;
        #pragma unroll 4
        for (int k4 = 0; k4 < 32; ++k4) {
            float4 wv0 = *(const float4*)(wp0 + (k4 << 2));
            float4 wv1 = *(const float4*)(wp1 + (k4 << 2));
            float4 wv2 = *(const float4*)(wp2 + (k4 << 2));
            float4 wv3 = *(const float4*)(wp3 + (k4 << 2));
            float4 a0  = *(const float4*)(l0 + (k4 << 2));
            float4 a1  = *(const float4*)(l1 + (k4 << 2));
            acc00 += a0.x*wv0.x; acc00 += a0.y*wv0.y; acc00 += a0.z*wv0.z; acc00 += a0.w*wv0.w;
            acc01 += a0.x*wv1.x; acc01 += a0.y*wv1.y; acc01 += a0.z*wv1.z; acc01 += a0.w*wv1.w;
            acc02 += a0.x*wv2.x; acc02 += a0.y*wv2.y; acc02 += a0.z*wv2.z; acc02 += a0.w*wv2.w;
            acc03 += a0.x*wv3.x; acc03 += a0.y*wv3.y; acc03 += a0.z*wv3.z; acc03 += a0.w*wv3.w;
            acc10 += a1.x*wv0.x; acc10 += a1.y*wv0.y; acc10 += a1.z*wv0.z; acc10 += a1.w*wv0.w;
            acc11 += a1.x*wv1.x; acc11 += a1.y*wv1.y; acc11 += a1.z*wv1.z; acc11 += a1.w*wv1.w;
            acc12 += a1.x*wv2.x; acc12 += a1.y*wv2.y; acc12 += a1.z*wv2.z; acc12 += a1.w*wv2.w;
            acc13 += a1.x*wv3.x; acc13 += a1.y*wv3.y; acc13 += a1.z*wv3.z; acc13 += a1.w*wv3.w;
        }
    }

    const size_t rowA = ((size_t)ks * 64 + b0 + bq) * 4096;
    const size_t rowB = ((size_t)ks * 64 + b0 + bq + 16) * 4096;
    gpart[rowA + 0 * 1024 + j] = acc00;
    gpart[rowA + 1 * 1024 + j] = acc01;
    gpart[rowA + 2 * 1024 + j] = acc02;
    gpart[rowA + 3 * 1024 + j] = acc03;
    gpart[rowB + 0 * 1024 + j] = acc10;
    gpart[rowB + 1 * 1024 + j] = acc11;
    gpart[rowB + 2 * 1024 + j] = acc12;
    gpart[rowB + 3 * 1024 + j] = acc13;
}

// ---------------------------------------------------------------------------
// Sum nsl k-slice partials + biases, LSTM pointwise, write h and c.
// ---------------------------------------------------------------------------
__global__ __launch_bounds__(256) void combine_cell(
    const float* __restrict__ gpart,
    const float* __restrict__ b_ih, const float* __restrict__ b_hh,
    float* c, float* __restrict__ h, int nsl)
{
    int el = blockIdx.x * 256 + threadIdx.x;
    int b = el >> 10, j = el & 1023;
    float g[4];
    #pragma unroll
    for (int gi = 0; gi < 4; ++gi)
        g[gi] = b_ih[gi * 1024 + j] + b_hh[gi * 1024 + j];
    for (int ksi = 0; ksi < nsl; ++ksi) {
        const float* row = gpart + ((size_t)ksi * 64 + b) * 4096 + j;
        #pragma unroll
        for (int gi = 0; gi < 4; ++gi)
            g[gi] += row[gi * 1024];
    }
    float ig = sigmoidf_(g[0]);
    float fg = sigmoidf_(g[1]);
    float gg = tanhf_(g[2]);
    float og = sigmoidf_(g[3]);
    float cn = fg * c[el] + ig * gg;
    c[el] = cn;
    h[el] = og * tanhf_(cn);
}

// ---------------------------------------------------------------------------
// q partial GEMM: qpart[ks][b][n] over k-slice of 256.
// ---------------------------------------------------------------------------
__global__ __launch_bounds__(256) void gemm_q(
    const float* __restrict__ h3, const float* __restrict__ w_proj,
    float* __restrict__ qpart)
{
    __shared__ float lds[32 * 132];
    const int tid = threadIdx.x;
    const int bq = tid & 15, nl = tid >> 4;
    const int bid = blockIdx.x;
    const int ng = bid & 31, ks = (bid >> 5) & 3, bh = bid >> 7;
    const int n = ng * 16 + nl;
    const int b0 = bh * 32;
    const float* wp = w_proj + (size_t)n * 1024 + (ks << 8);

    float acc0 = 0.f, acc1 = 0.f;
    for (int sub = 0; sub < 2; ++sub) {
        __syncthreads();
        #pragma unroll
        for (int it = 0; it < 4; ++it) {
            int idx = (it << 8) + tid;
            int r = idx >> 5, c4 = (idx & 31) << 2;
            float4 v = *(const float4*)(h3 + (size_t)(b0 + r) * 1024 + (ks << 8) + (sub << 7) + c4);
            float* d = lds + r * 132 + c4;
            d[0] = v.x; d[1] = v.y; d[2] = v.z; d[3] = v.w;
        }
        __syncthreads();
        const float* l0 = lds + bq * 132;
        const float* l1 = lds + (bq + 16) * 132;
        const float* wq = wp + (sub << 7);
        #pragma unroll 4
        for (int k4 = 0; k4 < 32; ++k4) {
            float4 wv = *(const float4*)(wq + (k4 << 2));
            float4 a0 = *(const float4*)(l0 + (k4 << 2));
            float4 a1 = *(const float4*)(l1 + (k4 << 2));
            acc0 += a0.x*wv.x; acc0 += a0.y*wv.y; acc0 += a0.z*wv.z; acc0 += a0.w*wv.w;
            acc1 += a1.x*wv.x; acc1 += a1.y*wv.y; acc1 += a1.z*wv.z; acc1 += a1.w*wv.w;
        }
    }
    qpart[((size_t)ks * 64 + b0 + bq) * 512 + n]      = acc0;
    qpart[((size_t)ks * 64 + b0 + bq + 16) * 512 + n] = acc1;
}

// ---------------------------------------------------------------------------
// Energy + online-softmax partials + weighted value partial sums.
// Grid 512 = 64 b x 8 s-chunks (50 s each).
// ---------------------------------------------------------------------------
__global__ __launch_bounds__(256) void energy_kernel(
    const float* __restrict__ qpart, const float* __restrict__ b_proj,
    const float* __restrict__ keys, const float* __restrict__ values,
    float* __restrict__ attn, int t,
    float* __restrict__ u_part, float* __restrict__ m_part, float* __restrict__ z_part)
{
    __shared__ float qs[4 * 132];
    __shared__ float es[64];
    __shared__ float ps[64];
    __shared__ float mz[1];
    const int tid = threadIdx.x;
    const int b   = blockIdx.x >> 3;
    const int ch  = blockIdx.x & 7;

    for (int k = tid; k < 512; k += 256) {
        float s = b_proj[k];
        #pragma unroll
        for (int ksi = 0; ksi < 4; ++ksi)
            s += qpart[((size_t)ksi * 64 + b) * 512 + k];
        qs[(k >> 7) * 132 + (k & 127)] = s;
    }
    __syncthreads();

    if (tid < 200) {
        int sl = tid >> 2, part = tid & 3;
        int s = ch * 50 + sl;
        const float* kr = keys + ((size_t)s * Bz + b) * Kd + part * 128;
        const float* qp = qs + part * 132;
        float e = 0.f;
        #pragma unroll 8
        for (int i4 = 0; i4 < 32; ++i4) {
            float4 kv = *(const float4*)(kr + (i4 << 2));
            e += qp[(i4 << 2) + 0] * kv.x;
            e += qp[(i4 << 2) + 1] * kv.y;
            e += qp[(i4 << 2) + 2] * kv.z;
            e += qp[(i4 << 2) + 3] * kv.w;
        }
        e += __shfl_down(e, 1);
        e += __shfl_down(e, 2);
        if (part == 0) es[sl] = e;
    }
    __syncthreads();
    if (tid == 0) {
        float m = -1e30f;
        for (int i = 0; i < 50; ++i) m = fmaxf(m, es[i]);
        mz[0] = m;
    }
    __syncthreads();
    float m = mz[0];
    if (tid < 50) {
        float p = __expf(es[tid] - m);
        ps[tid] = p;
        attn[(size_t)b * (Td * Sd) + t * Sd + ch * 50 + tid] = p;  // unnormalized
    }
    __syncthreads();
    if (tid == 0) {
        float z = 0.f;
        for (int i = 0; i < 50; ++i) z += ps[i];
        m_part[b * 8 + ch] = m;
        z_part[b * 8 + ch] = z;
    }
    float u0 = 0.f, u1 = 0.f;
    const float* vbase = values + ((size_t)(ch * 50) * Bz + b) * Kd;
    for (int s = 0; s < 50; ++s) {
        const float* vr = vbase + (size_t)s * Bz * Kd;
        float p = ps[s];
        u0 += p * vr[tid];
        u1 += p * vr[tid + 256];
    }
    u_part[((b << 3) + ch) * 512 + tid]       = u0;
    u_part[((b << 3) + ch) * 512 + tid + 256] = u1;
}

// ---------------------------------------------------------------------------
// Combine softmax partials -> ctx; normalize attention row; score.
// ---------------------------------------------------------------------------
__global__ __launch_bounds__(256) void finalize_kernel(
    const float* __restrict__ qpart, const float* __restrict__ b_proj,
    const float* __restrict__ u_part,
    const float* __restrict__ m_part, const float* __restrict__ z_part,
    float* __restrict__ ctx, float* __restrict__ attn, float* __restrict__ pred,
    const float* __restrict__ w_score, const float* __restrict__ b_score, int t)
{
    __shared__ float fc[8];
    __shared__ float qs[512];
    __shared__ float cs[512];
    const int tid = threadIdx.x;
    const int b = blockIdx.x;

    if (tid == 0) {
        float M = -1e30f;
        for (int c = 0; c < 8; ++c) M = fmaxf(M, m_part[b * 8 + c]);
        float f[8];
        float Z = 0.f;
        for (int c = 0; c < 8; ++c) {
            f[c] = __expf(m_part[b * 8 + c] - M);
            Z += z_part[b * 8 + c] * f[c];
        }
        float inv = 1.0f / Z;
        for (int c = 0; c < 8; ++c) fc[c] = f[c] * inv;
    }
    __syncthreads();

    for (int k = tid; k < 512; k += 256) {
        float s = b_proj[k];
        #pragma unroll
        for (int ksi = 0; ksi < 4; ++ksi)
            s += qpart[((size_t)ksi * 64 + b) * 512 + k];
        qs[k] = s;
        float acc = 0.f;
        #pragma unroll
        for (int c = 0; c < 8; ++c)
            acc += u_part[((b << 3) + c) * 512 + k] * fc[c];
        ctx[b * Kd + k] = acc;
        cs[k] = acc;
    }
    for (int s = tid; s < Sd; s += 256) {
        attn[(size_t)b * (Td * Sd) + t * Sd + s] *= fc[s / 50];
    }
    __syncthreads();

    if (tid < 136) {
        int v = tid >> 2, part = tid & 3;
        const float* wr = w_score + (size_t)v * 1024 + part * 256;
        const float* src = (part < 2) ? (qs + part * 256) : (cs + (part - 2) * 256);
        float acc = 0.f;
        #pragma unroll 8
        for (int i = 0; i < 256; ++i) acc += src[i] * wr[i];
        acc += __shfl_down(acc, 1);
        acc += __shfl_down(acc, 2);
        if (part == 0) pred[(size_t)b * (Td * Vd) + t * Vd + v] = acc + b_score[v];
    }
}

// ---------------------------------------------------------------------------
__global__ void init_states(const float* __restrict__ h0,
    float* h1, float* h2, float* h3, float* c1, float* c2, float* c3)
{
    int idx = blockIdx.x * 256 + threadIdx.x;
    int arr = idx >> 16;
    int off = idx & 65535;
    float v = h0[off & 1023];
    float* p;
    switch (arr) {
        case 0: p = h1; break;
        case 1: p = h2; break;
        case 2: p = h3; break;
        case 3: p = c1; break;
        case 4: p = c2; break;
        default: p = c3; break;
    }
    p[off] = v;
}

__global__ void init_ctx(const float* __restrict__ h0, const float* __restrict__ w_proj,
                         const float* __restrict__ b_proj, float* __restrict__ ctx)
{
    int k = blockIdx.x * 256 + threadIdx.x;
    float acc = b_proj[k];
    const float* wr = w_proj + (size_t)k * 1024;
    for (int j = 0; j < 1024; ++j) acc += h0[j] * wr[j];
    for (int b = 0; b < Bz; ++b) ctx[b * Kd + k] = acc;
}

// ---------------------------------------------------------------------------
extern "C" void kernel_launch(void* const* d_in, const int* in_sizes, int n_in,
                              void* d_out, int out_size, void* d_ws, size_t ws_size,
                              hipStream_t stream)
{
    (void)in_sizes; (void)n_in; (void)out_size;
    const int*   labels = (const int*)d_in[0];
    const float* keys   = (const float*)d_in[1];
    const float* values = (const float*)d_in[2];
    const float* emb    = (const float*)d_in[3];
    const float* w_ih0  = (const float*)d_in[4];
    const float* w_hh0  = (const float*)d_in[5];
    const float* b_ih0  = (const float*)d_in[6];
    const float* b_hh0  = (const float*)d_in[7];
    const float* w_ih1  = (const float*)d_in[8];
    const float* w_hh1  = (const float*)d_in[9];
    const float* b_ih1  = (const float*)d_in[10];
    const float* b_hh1  = (const float*)d_in[11];
    const float* w_ih2  = (const float*)d_in[12];
    const float* w_hh2  = (const float*)d_in[13];
    const float* b_ih2  = (const float*)d_in[14];
    const float* b_hh2  = (const float*)d_in[15];
    const float* w_proj = (const float*)d_in[16];
    const float* b_proj = (const float*)d_in[17];
    const float* w_score= (const float*)d_in[18];
    const float* b_score= (const float*)d_in[19];
    const float* h0     = (const float*)d_in[20];

    float* ws = (float*)d_ws;
    float* h1 = ws + 0;
    float* h2 = ws + 65536;
    float* h3 = ws + 131072;
    float* c1 = ws + 196608;
    float* c2 = ws + 262144;
    float* c3 = ws + 327680;
    float* ctx = ws + 393216;     // 64x512
    float* gpart = ws + 425984;   // up to 8 x 64 x 4096
    float* qpart = ws + 2523136;  // 4 x 64 x 512
    float* u_part = ws + 2654208; // 64 x 8 x 512
    float* m_part = ws + 2916352; // 512
    float* z_part = ws + 2916864; // 512
    // packed split-bf16 weights: 12 planes x 4096x1024 ushort, starts at float 2917376
    unsigned short* wp_base = (unsigned short*)(ws + 2917376);
    const size_t PLANE = (size_t)4096 * 1024;            // ushorts per plane
    const size_t NEED  = (size_t)2917376 * 4 + 12 * PLANE * 2;  // ~112.3 MB
    const bool fast = (ws_size >= NEED);

    unsigned short* Whi[3][2]; unsigned short* Wlo[3][2];
    const float* Wsrc[3][2] = {{w_ih0, w_hh0}, {w_ih1, w_hh1}, {w_ih2, w_hh2}};
    for (int c = 0; c < 3; ++c)
        for (int p = 0; p < 2; ++p) {
            Whi[c][p] = wp_base + ((size_t)(c * 2 + p) * 2 + 0) * PLANE;
            Wlo[c][p] = wp_base + ((size_t)(c * 2 + p) * 2 + 1) * PLANE;
        }

    float* pred = (float*)d_out;                        // [B,T,V]
    float* attn = (float*)d_out + (size_t)Bz * Td * Vd; // [B,T,S]

    if (fast) {
        const int n4 = (int)(PLANE / 4);
        for (int c = 0; c < 3; ++c)
            for (int p = 0; p < 2; ++p)
                pack_w_kernel<<<(n4 + 255) / 256, 256, 0, stream>>>(
                    Wsrc[c][p], Whi[c][p], Wlo[c][p], n4);
    }

    init_states<<<1536, 256, 0, stream>>>(h0, h1, h2, h3, c1, c2, c3);
    init_ctx<<<2, 256, 0, stream>>>(h0, w_proj, b_proj, ctx);

    const float* bih[3] = {b_ih0, b_ih1, b_ih2};
    const float* bhh[3] = {b_hh0, b_hh1, b_hh2};
    float* hs[3] = {h1, h2, h3};
    float* cs_[3] = {c1, c2, c3};

    for (int t = 0; t < Td; ++t) {
        for (int cell = 0; cell < 3; ++cell) {
            const float* x  = (cell == 0) ? emb : hs[cell - 1];
            const int mode  = (cell == 0) ? 0 : 1;
            if (fast) {
                gemm_cell_mfma<<<256, 256, 0, stream>>>(
                    x, labels, t, ctx, hs[cell],
                    Whi[cell][0], Wlo[cell][0], Whi[cell][1], Wlo[cell][1],
                    gpart, mode);
                combine_cell<<<256, 256, 0, stream>>>(gpart, bih[cell], bhh[cell],
                                                      cs_[cell], hs[cell], 8);
            } else {
                gemm_cell<<<512, 256, 0, stream>>>(
                    x, labels, t, ctx, hs[cell],
                    Wsrc[cell][0], Wsrc[cell][1], gpart, mode);
                combine_cell<<<256, 256, 0, stream>>>(gpart, bih[cell], bhh[cell],
                                                      cs_[cell], hs[cell], 4);
            }
        }
        gemm_q<<<256, 256, 0, stream>>>(h3, w_proj, qpart);
        energy_kernel<<<512, 256, 0, stream>>>(qpart, b_proj, keys, values, attn, t,
                                               u_part, m_part, z_part);
        finalize_kernel<<<64, 256, 0, stream>>>(qpart, b_proj, u_part, m_part, z_part,
                                                ctx, attn, pred, w_score, b_score, t);
    }
}